// Round 16
// baseline (8292.587 us; speedup 1.0000x reference)
//
#include <hip/hip_runtime.h>

#define BB 4
#define NN 16384
#define SS 4096
#define KK 16
#define KE 17                 // extended f32 list to expose boundary ties
#define PP 64
#define QQ 128

// flat FLOAT32 element offsets in d_out (return order: shapes, xyz_new, idx)
#define OFF_XYZNEW 2097152u   // 4*128*4096
#define OFF_IDX    2146304u   // + 4*4096*3
#define OUT_ELEMS  2408448u   // + 4*4096*16

// FPS: 512 threads (8 waves); x,y coords in LDS (thread-private slots),
// z + dist in registers.
#define FTH 512
#define FPT (NN / FTH)        // 32
#define NQUAD (FPT / 4)       // 8 float4 slots per thread
#define NWAVE (FTH / 64)      // 8

// KNN v2 (r11, byte-identical): 256 threads = 4 waves; wave-partitioned scan.
#define KTH 256
#define NW 4                  // scan partitions (= waves)
#define PART (NN / NW)        // 4096 candidates per partition
#define QPB 64                // queries per block
#define NBLK (SS / QPB)       // 64 blocks per batch
#define CAP 12                // per-lane LDS stack capacity
#define UU  8                 // candidates per drain-check batch
#define MARGIN 1e-3f          // >> worst-case |d32-d64| (~4e-5): f64 coverage proof

__device__ __forceinline__ float mulrn(float a, float b) { return __fmul_rn(a, b); }
__device__ __forceinline__ float addrn(float a, float b) { return __fadd_rn(a, b); }
__device__ __forceinline__ float subrn(float a, float b) { return __fsub_rn(a, b); }

// DPP argmax step, BRANCHLESS (r10-proven).
template<int CTRL>
__device__ __forceinline__ void dpp_amax(float& bv, int& bg)
{
    int vi = __builtin_amdgcn_update_dpp(__float_as_int(bv), __float_as_int(bv),
                                         CTRL, 0xf, 0xf, false);
    int gi = __builtin_amdgcn_update_dpp(bg, bg, CTRL, 0xf, 0xf, false);
    float ov = __int_as_float(vi);
    bool c = (ov > bv) | ((ov == bv) & (gi < bg));   // bitwise: no short-circuit branch
    bg = c ? gi : bg;
    bv = c ? ov : bv;
}

// ---------------------------------------------------------------------------
// Kernel 1: farthest point sampling, 1 block per batch.
// v14 (resubmitted -- r15 bench was an infra failure, kernel never ran):
// storage off the allocator. Five rounds of evidence (r2/r7/r12/r13/r14):
// issue ~3000 cyc/iter invariant under inner-loop form because the
// allocator parks the coord arrays in AGPRs and the v_accvgpr moves execute
// on the VALU pipe, serializing with the math. Fix: x,y live in LDS as
// THREAD-PRIVATE slots (xs4[k][tid] written and read only by thread tid --
// no barrier ever needed for them); z + dist (64 floats) stay in registers.
// The storage traffic moves to the DS pipe (16 ds_read_b128/thread/iter,
// ~1536 cyc/CU) and overlaps the VALU math instead of serializing with it.
// LICM hazard: the LDS loads are provably loop-invariant; an asm-laundered
// byte offset inside the s-loop stops the compiler from hoisting them back
// into registers (which would recreate the parking).
// 128 KB static LDS: r9 forensics PROVED r4's 96KB-LDS fps ran correctly
// (bit-identical downstream vs two known-good fps variants); HW limit 160KB.
// Exactness: per-point chain is the r3-verified scalar sub/mul/add/fminf
// (same bits -- same floats, different storage); ascending-j visit order;
// strict '>' with r14-proven bj tracking; DPP ladder, uint2 scan, s_load
// winner reload, single barrier/iter byte-identical to r14.
// ---------------------------------------------------------------------------
__global__ __launch_bounds__(FTH)
__attribute__((amdgpu_waves_per_eu(2, 2)))
void fps_kernel(
    const float* __restrict__ xyz,
    float* __restrict__ out,
    float* __restrict__ ws, unsigned ws_floats)
{
    __shared__ float4 xs4[NQUAD][FTH];   // 64 KB: x coords, thread-private slots
    __shared__ float4 ys4[NQUAD][FTH];   // 64 KB: y coords
    __shared__ uint2  wvg[2][NWAVE];     // packed (v_bits, g) per wave

    const int b   = blockIdx.x;
    const int tid = threadIdx.x;
    const float* base = xyz + (size_t)b * NN * 3;

    float pz_[FPT], dist[FPT];
#pragma unroll
    for (int k = 0; k < NQUAD; ++k) {
        float4 xv, yv;
#pragma unroll
        for (int u = 0; u < 4; ++u) {
            int j = 4 * k + u;
            int g = tid + FTH * j;
            ((float*)&xv)[u] = base[g * 3 + 0];
            ((float*)&yv)[u] = base[g * 3 + 1];
            pz_[j]   = base[g * 3 + 2];
            dist[j]  = 1e10f;
        }
        xs4[k][tid] = xv;
        ys4[k][tid] = yv;
    }
#pragma unroll
    for (int j = 0; j < FPT; ++j) asm volatile("" : "+v"(pz_[j]));

    float lx = base[0], ly = base[1], lz = base[2];
    if (tid == 0) {
        unsigned o = OFF_XYZNEW + (unsigned)b * SS * 3u;
        out[o + 0] = lx; out[o + 1] = ly; out[o + 2] = lz;
        unsigned w = (unsigned)b * SS * 3u;
        if (w + 2u < ws_floats) { ws[w] = lx; ws[w + 1] = ly; ws[w + 2] = lz; }
    }

    const int lane = tid & 63;
    const int wave = tid >> 6;
    const unsigned toff = (unsigned)tid * 16u;   // byte offset of this thread's slot 0
    int p = 0;

    for (int s = 1; s < SS; ++s) {
        // launder the LDS offset so loop-invariant ds_reads can't be hoisted
        unsigned o2 = toff;
        asm volatile("" : "+v"(o2));
        const char* xbase = (const char*)&xs4[0][0] + o2;
        const char* ybase = (const char*)&ys4[0][0] + o2;

        float bestv = -1.0f;
        int   bj    = 0;
#pragma unroll
        for (int k = 0; k < NQUAD; ++k) {
            float4 X = *(const float4*)(xbase + (unsigned)k * (FTH * 16u));
            float4 Y = *(const float4*)(ybase + (unsigned)k * (FTH * 16u));
#pragma unroll
            for (int u = 0; u < 4; ++u) {
                int j = 4 * k + u;
                float dx = subrn(((const float*)&X)[u], lx);
                float dy = subrn(((const float*)&Y)[u], ly);
                float dz = subrn(pz_[j], lz);
                float d  = addrn(addrn(mulrn(dx, dx), mulrn(dy, dy)), mulrn(dz, dz));
                float nd = fminf(dist[j], d);
                dist[j] = nd;
                // BRANCHLESS, ascending-j visit order, strict '>' => identical ties
                bj    = (nd > bestv) ? j : bj;
                bestv = fmaxf(bestv, nd);
            }
        }
        int bestg = tid + FTH * bj;   // single reconstruction (g monotone in j)

        // wave argmax via DPP (VALU-only): result in lane 63
        dpp_amax<0x111>(bestv, bestg);   // row_shr:1
        dpp_amax<0x112>(bestv, bestg);   // row_shr:2
        dpp_amax<0x114>(bestv, bestg);   // row_shr:4
        dpp_amax<0x118>(bestv, bestg);   // row_shr:8
        dpp_amax<0x142>(bestv, bestg);   // row_bcast:15
        dpp_amax<0x143>(bestv, bestg);   // row_bcast:31

        if (lane == 63) wvg[p][wave] = make_uint2(__float_as_uint(bestv), (unsigned)bestg);
        __syncthreads();
        // single barrier: buffer p reads below are ordered before any write to
        // buffer p^1 (next iter); buffer p is only rewritten two iters later.

        uint2 e0 = wvg[p][0];
        float bv = __uint_as_float(e0.x); int bg = (int)e0.y;
#pragma unroll
        for (int w = 1; w < NWAVE; ++w) {
            uint2 e = wvg[p][w];
            float v = __uint_as_float(e.x); int g = (int)e.y;
            bool c = (v > bv) | ((v == bv) & (g < bg));
            bg = c ? g : bg;
            bv = c ? v : bv;
        }

        int bgu = __builtin_amdgcn_readfirstlane(bg);
        lx = base[bgu * 3 + 0];
        ly = base[bgu * 3 + 1];
        lz = base[bgu * 3 + 2];

        if (tid == 0) {
            unsigned o = OFF_XYZNEW + ((unsigned)b * SS + (unsigned)s) * 3u;
            out[o + 0] = lx; out[o + 1] = ly; out[o + 2] = lz;
            unsigned w = ((unsigned)b * SS + (unsigned)s) * 3u;
            if (w + 2u < ws_floats) { ws[w] = lx; ws[w + 1] = ly; ws[w + 2] = lz; }
        }
        p ^= 1;
    }
}

// ---------------------------------------------------------------------------
// Kernel 2 v2: BYTE-IDENTICAL to r11/r14 (passing). Partitioned scan + exact
// merge (ascending-g replay with identical chains -> bit-identical lists).
// ---------------------------------------------------------------------------
__global__ __launch_bounds__(KTH) void knn_shape_kernel(
    const float* __restrict__ xyz,
    const float* __restrict__ ws, int use_ws, unsigned ws_floats,
    const float* __restrict__ w_planes, const float* __restrict__ w_shapes,
    const float* __restrict__ bn_gamma, const float* __restrict__ bn_beta,
    const float* __restrict__ bn_mean, const float* __restrict__ bn_var,
    float* __restrict__ out)
{
    __shared__ float sd[CAP][KTH];    // 12 KB
    __shared__ int   sg[CAP][KTH];    // 12 KB
    __shared__ float wpx[PP], wpy[PP], wpz[PP];
    __shared__ float bsc[QQ], bmn[QQ], bbt[QQ];
    __shared__ int   ski[NW][KE][QPB];    // 17 KB
    __shared__ int   ski64[NW][KK][QPB];  // 16 KB

    const int tid  = threadIdx.x;
    const int lane = tid & 63;            // query slot within block
    const int w    = tid >> 6;            // scan partition (= wave)
    const int blk  = blockIdx.x;
    const int b    = blk / NBLK;
    const int s    = (blk % NBLK) * QPB + lane;   // [0, 4096)

    for (int i = tid; i < PP; i += KTH) {
        wpx[i] = w_planes[i * 3 + 0];
        wpy[i] = w_planes[i * 3 + 1];
        wpz[i] = w_planes[i * 3 + 2];
    }
    for (int i = tid; i < QQ; i += KTH) {
        bsc[i] = bn_gamma[i] / sqrtf(bn_var[i] + 1e-5f);
        bmn[i] = bn_mean[i];
        bbt[i] = bn_beta[i];
    }
    __syncthreads();

    const float* bx = xyz + (size_t)b * NN * 3;

    float qx, qy, qz;
    {
        unsigned wq = ((unsigned)b * SS + (unsigned)s) * 3u;
        if (use_ws && wq + 2u < ws_floats) {
            qx = ws[wq]; qy = ws[wq + 1]; qz = ws[wq + 2];
        } else {
            unsigned o = OFF_XYZNEW + wq;
            qx = out[o + 0]; qy = out[o + 1]; qz = out[o + 2];
        }
    }
    const float  qsq   = addrn(addrn(mulrn(qx, qx), mulrn(qy, qy)), mulrn(qz, qz));
    const double qxd = (double)qx, qyd = (double)qy, qzd = (double)qz;
    const double qsq64 = qxd * qxd + qyd * qyd + qzd * qzd;

    float  kd[KE];   int ki[KE];
    double kd64[KK]; int ki64[KK];
#pragma unroll
    for (int t = 0; t < KE; ++t) { kd[t] = 3.0e38f; ki[t] = 0; }
#pragma unroll
    for (int t = 0; t < KK; ++t) { kd64[t] = 1.0e300; ki64[t] = 0; }

    int   cnt  = 0;
    float taum = 3.0e38f;

    auto drain = [&]() {
        for (int t = 0; t < CAP; ++t) {
            if (!__any(t < cnt)) break;
            const bool act = t < cnt;
            float d = 0.0f; int g = 0;
            if (act) { d = sd[t][tid]; g = sg[t][tid]; }
            if (act) {
                if (d < kd[KE - 1]) {
                    kd[KE - 1] = d; ki[KE - 1] = g;
#pragma unroll
                    for (int t2 = KE - 1; t2 >= 1; --t2) {
                        if (kd[t2] < kd[t2 - 1]) {
                            float td = kd[t2]; kd[t2] = kd[t2 - 1]; kd[t2 - 1] = td;
                            int   ti = ki[t2]; ki[t2] = ki[t2 - 1]; ki[t2 - 1] = ti;
                        }
                    }
                }
                const float* pg = bx + (size_t)g * 3u;
                float x = pg[0], y = pg[1], z = pg[2];
                double xd = (double)x, yd = (double)y, zd = (double)z;
                double tq64  = xd * xd + yd * yd + zd * zd;
                double dot64 = xd * qxd + yd * qyd + zd * qzd;
                double d64   = qsq64 + tq64 - 2.0 * dot64;
                if (d64 < kd64[KK - 1]) {
                    kd64[KK - 1] = d64; ki64[KK - 1] = g;
#pragma unroll
                    for (int t2 = KK - 1; t2 >= 1; --t2) {
                        if (kd64[t2] < kd64[t2 - 1]) {
                            double td = kd64[t2]; kd64[t2] = kd64[t2 - 1]; kd64[t2 - 1] = td;
                            int    ti = ki64[t2]; ki64[t2] = ki64[t2 - 1]; ki64[t2 - 1] = ti;
                        }
                    }
                }
            }
        }
        cnt  = 0;
        taum = kd[KE - 1] + MARGIN;
    };

    const int gbeg = w * PART;
    for (int g0 = gbeg; g0 < gbeg + PART; g0 += UU) {
        float4 c4[6];
        const float4* p4 = reinterpret_cast<const float4*>(bx + (size_t)g0 * 3u);
#pragma unroll
        for (int i = 0; i < 6; ++i) c4[i] = p4[i];
        const float* cf = reinterpret_cast<const float*>(c4);
#pragma unroll
        for (int u = 0; u < UU; ++u) {
            int g = g0 + u;
            float x = cf[u * 3 + 0];
            float y = cf[u * 3 + 1];
            float z = cf[u * 3 + 2];
            float tq  = addrn(addrn(mulrn(x, x), mulrn(y, y)), mulrn(z, z));
            float dot = fmaf(z, qz, fmaf(y, qy, mulrn(x, qx)));
            float d   = subrn(addrn(qsq, tq), mulrn(2.0f, dot));
            if (d < taum) { sd[cnt][tid] = d; sg[cnt][tid] = g; ++cnt; }
        }
        if (__any(cnt > CAP - UU)) drain();
    }
    drain();

#pragma unroll
    for (int t = 0; t < KE; ++t) ski[w][t][lane] = ki[t];
#pragma unroll
    for (int t = 0; t < KK; ++t) ski64[w][t][lane] = ki64[t];
    __syncthreads();

    if (tid < QPB) {
        float  kdm[KE]; int kim[KE];
        double k64m[KK]; int i64m[KK];
#pragma unroll
        for (int t = 0; t < KE; ++t) { kdm[t] = 3.0e38f; kim[t] = 0; }
#pragma unroll
        for (int t = 0; t < KK; ++t) { k64m[t] = 1.0e300; i64m[t] = 0; }

        for (int w2 = 0; w2 < NW; ++w2) {
            int gs[KE];
#pragma unroll
            for (int t = 0; t < KE; ++t) gs[t] = ski[w2][t][lane];
            for (int a = 1; a < KE; ++a) {
                int key = gs[a]; int bi = a - 1;
                while (bi >= 0 && gs[bi] > key) { gs[bi + 1] = gs[bi]; --bi; }
                gs[bi + 1] = key;
            }
            for (int t = 0; t < KE; ++t) {
                int g = gs[t];
                float x = bx[g * 3 + 0];
                float y = bx[g * 3 + 1];
                float z = bx[g * 3 + 2];
                float tq  = addrn(addrn(mulrn(x, x), mulrn(y, y)), mulrn(z, z));
                float dot = fmaf(z, qz, fmaf(y, qy, mulrn(x, qx)));
                float d   = subrn(addrn(qsq, tq), mulrn(2.0f, dot));
                if (d < kdm[KE - 1]) {
                    kdm[KE - 1] = d; kim[KE - 1] = g;
#pragma unroll
                    for (int t2 = KE - 1; t2 >= 1; --t2) {
                        if (kdm[t2] < kdm[t2 - 1]) {
                            float td = kdm[t2]; kdm[t2] = kdm[t2 - 1]; kdm[t2 - 1] = td;
                            int   ti = kim[t2]; kim[t2] = kim[t2 - 1]; kim[t2 - 1] = ti;
                        }
                    }
                }
            }
        }
        for (int w2 = 0; w2 < NW; ++w2) {
            int gs[KK];
#pragma unroll
            for (int t = 0; t < KK; ++t) gs[t] = ski64[w2][t][lane];
            for (int a = 1; a < KK; ++a) {
                int key = gs[a]; int bi = a - 1;
                while (bi >= 0 && gs[bi] > key) { gs[bi + 1] = gs[bi]; --bi; }
                gs[bi + 1] = key;
            }
            for (int t = 0; t < KK; ++t) {
                int g = gs[t];
                const float* pg = bx + (size_t)g * 3u;
                float x = pg[0], y = pg[1], z = pg[2];
                double xd = (double)x, yd = (double)y, zd = (double)z;
                double tq64  = xd * xd + yd * yd + zd * zd;
                double dot64 = xd * qxd + yd * qyd + zd * qzd;
                double d64   = qsq64 + tq64 - 2.0 * dot64;
                if (d64 < k64m[KK - 1]) {
                    k64m[KK - 1] = d64; i64m[KK - 1] = g;
#pragma unroll
                    for (int t2 = KK - 1; t2 >= 1; --t2) {
                        if (k64m[t2] < k64m[t2 - 1]) {
                            double td = k64m[t2]; k64m[t2] = k64m[t2 - 1]; k64m[t2 - 1] = td;
                            int    ti = i64m[t2]; i64m[t2] = i64m[t2 - 1]; i64m[t2 - 1] = ti;
                        }
                    }
                }
            }
        }

        bool agree = true;
#pragma unroll
        for (int t = 0; t < KK; ++t) agree = agree && (kim[t] == i64m[t]);

        bool hastie = false;
#pragma unroll
        for (int t = 1; t < KE; ++t) hastie = hastie || (kdm[t] == kdm[t - 1]);

        const bool use_f32 = agree || hastie;
        int kf[KK];
#pragma unroll
        for (int t = 0; t < KK; ++t) kf[t] = use_f32 ? kim[t] : i64m[t];

        float pl[PP];
#pragma unroll
        for (int p = 0; p < PP; ++p) pl[p] = -3.0e38f;

        for (int k = 1; k < KK; ++k) {
            int g = kf[k];
            float rx = bx[g * 3 + 0] - qx;
            float ry = bx[g * 3 + 1] - qy;
            float rz = bx[g * 3 + 2] - qz;
            float nrm  = sqrtf(rx * rx + ry * ry + rz * rz) + 1e-8f;
            float invn = 1.0f / nrm;
            for (int p = 0; p < PP; ++p) {
                float t = rx * wpx[p] + ry * wpy[p] + rz * wpz[p];
                float a = t * invn;
                float v = nrm * a * fabsf(a);
                pl[p] = fmaxf(pl[p], v);
            }
        }

        for (int q = 0; q < QQ; ++q) {
            float acc = 0.0f;
            for (int p = 0; p < PP; ++p) acc = fmaf(pl[p], w_shapes[q * PP + p], acc);
            float y2 = (acc - bmn[q]) * bsc[q] + bbt[q];
            y2 = fmaxf(y2, 0.0f);
            unsigned o = ((unsigned)b * QQ + (unsigned)q) * SS + (unsigned)s;
            out[o] = y2;
        }

        for (int t = 0; t < KK; ++t) {
            unsigned o = OFF_IDX + ((unsigned)b * SS + (unsigned)s) * (unsigned)KK + (unsigned)t;
            out[o] = (float)kf[t];
        }
    }
}

extern "C" void kernel_launch(void* const* d_in, const int* in_sizes, int n_in,
                              void* d_out, int out_size, void* d_ws, size_t ws_size,
                              hipStream_t stream)
{
    const float* xyz      = (const float*)d_in[0];
    const float* w_planes = (const float*)d_in[1];
    const float* w_shapes = (const float*)d_in[2];
    const float* bn_gamma = (const float*)d_in[3];
    const float* bn_beta  = (const float*)d_in[4];
    const float* bn_mean  = (const float*)d_in[5];
    const float* bn_var   = (const float*)d_in[6];

    float* out = (float*)d_out;
    float* ws  = (float*)d_ws;

    const unsigned ws_floats = (unsigned)(ws_size / 4);
    const int use_ws = (ws_size >= (size_t)BB * SS * 3 * 4) ? 1 : 0;

    hipLaunchKernelGGL(fps_kernel, dim3(BB), dim3(FTH), 0, stream,
                       xyz, out, ws, ws_floats);

    hipLaunchKernelGGL(knn_shape_kernel, dim3(BB * NBLK), dim3(KTH), 0, stream,
                       xyz, ws, use_ws, ws_floats,
                       w_planes, w_shapes,
                       bn_gamma, bn_beta, bn_mean, bn_var,
                       out);
}

// Round 17
// 7389.245 us; speedup vs baseline: 1.1223x; 1.1223x over previous
//
#include <hip/hip_runtime.h>

#define BB 4
#define NN 16384
#define SS 4096
#define KK 16
#define KE 17                 // extended f32 list to expose boundary ties
#define PP 64
#define QQ 128

// flat FLOAT32 element offsets in d_out (return order: shapes, xyz_new, idx)
#define OFF_XYZNEW 2097152u   // 4*128*4096
#define OFF_IDX    2146304u   // + 4*4096*3
#define OUT_ELEMS  2408448u   // + 4*4096*16

// FPS: 512 threads (8 waves) -- r10/r11/r14 config (measured optimum).
#define FTH 512
#define FPT (NN / FTH)        // 32
#define PAIRS (FPT / 2)       // 16
#define NWAVE (FTH / 64)      // 8

// KNN v2 (r11, byte-identical): 256 threads = 4 waves; wave-partitioned scan.
#define KTH 256
#define NW 4                  // scan partitions (= waves)
#define PART (NN / NW)        // 4096 candidates per partition
#define QPB 64                // queries per block
#define NBLK (SS / QPB)       // 64 blocks per batch
#define CAP 12                // per-lane LDS stack capacity
#define UU  8                 // candidates per drain-check batch
#define MARGIN 1e-3f          // >> worst-case |d32-d64| (~4e-5): f64 coverage proof

typedef float float2v __attribute__((ext_vector_type(2)));

__device__ __forceinline__ float mulrn(float a, float b) { return __fmul_rn(a, b); }
__device__ __forceinline__ float addrn(float a, float b) { return __fadd_rn(a, b); }
__device__ __forceinline__ float subrn(float a, float b) { return __fsub_rn(a, b); }

// DPP argmax step, BRANCHLESS (r10-proven).
template<int CTRL>
__device__ __forceinline__ void dpp_amax(float& bv, int& bg)
{
    int vi = __builtin_amdgcn_update_dpp(__float_as_int(bv), __float_as_int(bv),
                                         CTRL, 0xf, 0xf, false);
    int gi = __builtin_amdgcn_update_dpp(bg, bg, CTRL, 0xf, 0xf, false);
    float ov = __int_as_float(vi);
    bool c = (ov > bv) | ((ov == bv) & (gi < bg));   // bitwise: no short-circuit branch
    bg = c ? gi : bg;
    bv = c ? ov : bv;
}

// ---------------------------------------------------------------------------
// Kernel 1: farthest point sampling, 1 block per batch.
// FINAL (= r14, best measured: 6507us warm). FTH=512, waves_per_eu(2,2),
// packed float2 inner loop, branchless selects with bj index tracking
// (inline-const cndmask; bestg reconstructed once -- g = tid+FTH*j monotone
// in j), DPP wave argmax, uint2 LDS stage, single barrier/iter,
// readfirstlane+s_load winner reload.
// Structural-ceiling note: six falsified attacks (r2 pins, r7 FPT=16,
// r12 asm-VOP3P, r13 waves(1,1), r14 bj-only -1.5%, r16 LDS-relocation)
// establish that the ~3000 issue-cyc/iter is not removable at HIP source
// level; the serial-iteration floor (~2300 cyc/iter on 4 CUs) is the
// binding constraint of the exact-chain FPS algorithm.
// ---------------------------------------------------------------------------
__global__ __launch_bounds__(FTH)
__attribute__((amdgpu_waves_per_eu(2, 2)))
void fps_kernel(
    const float* __restrict__ xyz,
    float* __restrict__ out,
    float* __restrict__ ws, unsigned ws_floats)
{
    const int b   = blockIdx.x;
    const int tid = threadIdx.x;
    const float* base = xyz + (size_t)b * NN * 3;

    float2v pxx[PAIRS], pyy[PAIRS], pzz[PAIRS], pdd[PAIRS];
#pragma unroll
    for (int i = 0; i < PAIRS; ++i) {
        int g0 = tid + FTH * (2 * i);
        int g1 = tid + FTH * (2 * i + 1);
        pxx[i] = (float2v){ base[g0 * 3 + 0], base[g1 * 3 + 0] };
        pyy[i] = (float2v){ base[g0 * 3 + 1], base[g1 * 3 + 1] };
        pzz[i] = (float2v){ base[g0 * 3 + 2], base[g1 * 3 + 2] };
        pdd[i] = (float2v){ 1e10f, 1e10f };
        asm volatile("" : "+v"(pxx[i]));
        asm volatile("" : "+v"(pyy[i]));
        asm volatile("" : "+v"(pzz[i]));
    }

    __shared__ uint2 wvg[2][NWAVE];   // packed (v_bits, g) per wave

    float lx = base[0], ly = base[1], lz = base[2];
    if (tid == 0) {
        unsigned o = OFF_XYZNEW + (unsigned)b * SS * 3u;
        out[o + 0] = lx; out[o + 1] = ly; out[o + 2] = lz;
        unsigned w = (unsigned)b * SS * 3u;
        if (w + 2u < ws_floats) { ws[w] = lx; ws[w + 1] = ly; ws[w + 2] = lz; }
    }

    const int lane = tid & 63;
    const int wave = tid >> 6;
    int p = 0;

    for (int s = 1; s < SS; ++s) {
#pragma clang fp contract(off)
        const float2v lx2 = (float2v){ lx, lx };
        const float2v ly2 = (float2v){ ly, ly };
        const float2v lz2 = (float2v){ lz, lz };
        float bestv = -1.0f;
        int   bj    = 0;
#pragma unroll
        for (int i = 0; i < PAIRS; ++i) {
            float2v dx = pxx[i] - lx2;                    // IEEE sub, rn, per elem
            float2v dy = pyy[i] - ly2;
            float2v dz = pzz[i] - lz2;
            float2v dd = (dx * dx + dy * dy) + dz * dz;   // contract off: mul,mul,add,mul,add
            float n0 = fminf(pdd[i].x, dd.x);
            float n1 = fminf(pdd[i].y, dd.y);
            pdd[i] = (float2v){ n0, n1 };
            // BRANCHLESS, ascending-j visit order, strict '>' => identical ties.
            // j is an inline constant -> v_cndmask with const operand, no v_add.
            bj    = (n0 > bestv) ? (2 * i)     : bj;
            bestv = fmaxf(bestv, n0);
            bj    = (n1 > bestv) ? (2 * i + 1) : bj;
            bestv = fmaxf(bestv, n1);
        }
        int bestg = tid + FTH * bj;   // single reconstruction (g monotone in j)

        // wave argmax via DPP (VALU-only): result in lane 63
        dpp_amax<0x111>(bestv, bestg);   // row_shr:1
        dpp_amax<0x112>(bestv, bestg);   // row_shr:2
        dpp_amax<0x114>(bestv, bestg);   // row_shr:4
        dpp_amax<0x118>(bestv, bestg);   // row_shr:8
        dpp_amax<0x142>(bestv, bestg);   // row_bcast:15
        dpp_amax<0x143>(bestv, bestg);   // row_bcast:31

        if (lane == 63) wvg[p][wave] = make_uint2(__float_as_uint(bestv), (unsigned)bestg);
        __syncthreads();
        // single barrier: buffer p reads below are ordered before any write to
        // buffer p^1 (next iter); buffer p is only rewritten two iters later.

        uint2 e0 = wvg[p][0];
        float bv = __uint_as_float(e0.x); int bg = (int)e0.y;
#pragma unroll
        for (int w = 1; w < NWAVE; ++w) {
            uint2 e = wvg[p][w];
            float v = __uint_as_float(e.x); int g = (int)e.y;
            bool c = (v > bv) | ((v == bv) & (g < bg));
            bg = c ? g : bg;
            bv = c ? v : bv;
        }

        int bgu = __builtin_amdgcn_readfirstlane(bg);
        lx = base[bgu * 3 + 0];
        ly = base[bgu * 3 + 1];
        lz = base[bgu * 3 + 2];

        if (tid == 0) {
            unsigned o = OFF_XYZNEW + ((unsigned)b * SS + (unsigned)s) * 3u;
            out[o + 0] = lx; out[o + 1] = ly; out[o + 2] = lz;
            unsigned w = ((unsigned)b * SS + (unsigned)s) * 3u;
            if (w + 2u < ws_floats) { ws[w] = lx; ws[w + 1] = ly; ws[w + 2] = lz; }
        }
        p ^= 1;
    }
}

// ---------------------------------------------------------------------------
// Kernel 2 v2: BYTE-IDENTICAL to r11/r14 (passing). Partitioned scan + exact
// merge (ascending-g replay with identical chains -> bit-identical lists).
// ---------------------------------------------------------------------------
__global__ __launch_bounds__(KTH) void knn_shape_kernel(
    const float* __restrict__ xyz,
    const float* __restrict__ ws, int use_ws, unsigned ws_floats,
    const float* __restrict__ w_planes, const float* __restrict__ w_shapes,
    const float* __restrict__ bn_gamma, const float* __restrict__ bn_beta,
    const float* __restrict__ bn_mean, const float* __restrict__ bn_var,
    float* __restrict__ out)
{
    __shared__ float sd[CAP][KTH];    // 12 KB
    __shared__ int   sg[CAP][KTH];    // 12 KB
    __shared__ float wpx[PP], wpy[PP], wpz[PP];
    __shared__ float bsc[QQ], bmn[QQ], bbt[QQ];
    __shared__ int   ski[NW][KE][QPB];    // 17 KB
    __shared__ int   ski64[NW][KK][QPB];  // 16 KB

    const int tid  = threadIdx.x;
    const int lane = tid & 63;            // query slot within block
    const int w    = tid >> 6;            // scan partition (= wave)
    const int blk  = blockIdx.x;
    const int b    = blk / NBLK;
    const int s    = (blk % NBLK) * QPB + lane;   // [0, 4096)

    for (int i = tid; i < PP; i += KTH) {
        wpx[i] = w_planes[i * 3 + 0];
        wpy[i] = w_planes[i * 3 + 1];
        wpz[i] = w_planes[i * 3 + 2];
    }
    for (int i = tid; i < QQ; i += KTH) {
        bsc[i] = bn_gamma[i] / sqrtf(bn_var[i] + 1e-5f);
        bmn[i] = bn_mean[i];
        bbt[i] = bn_beta[i];
    }
    __syncthreads();

    const float* bx = xyz + (size_t)b * NN * 3;

    float qx, qy, qz;
    {
        unsigned wq = ((unsigned)b * SS + (unsigned)s) * 3u;
        if (use_ws && wq + 2u < ws_floats) {
            qx = ws[wq]; qy = ws[wq + 1]; qz = ws[wq + 2];
        } else {
            unsigned o = OFF_XYZNEW + wq;
            qx = out[o + 0]; qy = out[o + 1]; qz = out[o + 2];
        }
    }
    const float  qsq   = addrn(addrn(mulrn(qx, qx), mulrn(qy, qy)), mulrn(qz, qz));
    const double qxd = (double)qx, qyd = (double)qy, qzd = (double)qz;
    const double qsq64 = qxd * qxd + qyd * qyd + qzd * qzd;

    float  kd[KE];   int ki[KE];
    double kd64[KK]; int ki64[KK];
#pragma unroll
    for (int t = 0; t < KE; ++t) { kd[t] = 3.0e38f; ki[t] = 0; }
#pragma unroll
    for (int t = 0; t < KK; ++t) { kd64[t] = 1.0e300; ki64[t] = 0; }

    int   cnt  = 0;
    float taum = 3.0e38f;

    auto drain = [&]() {
        for (int t = 0; t < CAP; ++t) {
            if (!__any(t < cnt)) break;
            const bool act = t < cnt;
            float d = 0.0f; int g = 0;
            if (act) { d = sd[t][tid]; g = sg[t][tid]; }
            if (act) {
                if (d < kd[KE - 1]) {
                    kd[KE - 1] = d; ki[KE - 1] = g;
#pragma unroll
                    for (int t2 = KE - 1; t2 >= 1; --t2) {
                        if (kd[t2] < kd[t2 - 1]) {
                            float td = kd[t2]; kd[t2] = kd[t2 - 1]; kd[t2 - 1] = td;
                            int   ti = ki[t2]; ki[t2] = ki[t2 - 1]; ki[t2 - 1] = ti;
                        }
                    }
                }
                const float* pg = bx + (size_t)g * 3u;
                float x = pg[0], y = pg[1], z = pg[2];
                double xd = (double)x, yd = (double)y, zd = (double)z;
                double tq64  = xd * xd + yd * yd + zd * zd;
                double dot64 = xd * qxd + yd * qyd + zd * qzd;
                double d64   = qsq64 + tq64 - 2.0 * dot64;
                if (d64 < kd64[KK - 1]) {
                    kd64[KK - 1] = d64; ki64[KK - 1] = g;
#pragma unroll
                    for (int t2 = KK - 1; t2 >= 1; --t2) {
                        if (kd64[t2] < kd64[t2 - 1]) {
                            double td = kd64[t2]; kd64[t2] = kd64[t2 - 1]; kd64[t2 - 1] = td;
                            int    ti = ki64[t2]; ki64[t2] = ki64[t2 - 1]; ki64[t2 - 1] = ti;
                        }
                    }
                }
            }
        }
        cnt  = 0;
        taum = kd[KE - 1] + MARGIN;
    };

    const int gbeg = w * PART;
    for (int g0 = gbeg; g0 < gbeg + PART; g0 += UU) {
        float4 c4[6];
        const float4* p4 = reinterpret_cast<const float4*>(bx + (size_t)g0 * 3u);
#pragma unroll
        for (int i = 0; i < 6; ++i) c4[i] = p4[i];
        const float* cf = reinterpret_cast<const float*>(c4);
#pragma unroll
        for (int u = 0; u < UU; ++u) {
            int g = g0 + u;
            float x = cf[u * 3 + 0];
            float y = cf[u * 3 + 1];
            float z = cf[u * 3 + 2];
            float tq  = addrn(addrn(mulrn(x, x), mulrn(y, y)), mulrn(z, z));
            float dot = fmaf(z, qz, fmaf(y, qy, mulrn(x, qx)));
            float d   = subrn(addrn(qsq, tq), mulrn(2.0f, dot));
            if (d < taum) { sd[cnt][tid] = d; sg[cnt][tid] = g; ++cnt; }
        }
        if (__any(cnt > CAP - UU)) drain();
    }
    drain();

#pragma unroll
    for (int t = 0; t < KE; ++t) ski[w][t][lane] = ki[t];
#pragma unroll
    for (int t = 0; t < KK; ++t) ski64[w][t][lane] = ki64[t];
    __syncthreads();

    if (tid < QPB) {
        float  kdm[KE]; int kim[KE];
        double k64m[KK]; int i64m[KK];
#pragma unroll
        for (int t = 0; t < KE; ++t) { kdm[t] = 3.0e38f; kim[t] = 0; }
#pragma unroll
        for (int t = 0; t < KK; ++t) { k64m[t] = 1.0e300; i64m[t] = 0; }

        for (int w2 = 0; w2 < NW; ++w2) {
            int gs[KE];
#pragma unroll
            for (int t = 0; t < KE; ++t) gs[t] = ski[w2][t][lane];
            for (int a = 1; a < KE; ++a) {
                int key = gs[a]; int bi = a - 1;
                while (bi >= 0 && gs[bi] > key) { gs[bi + 1] = gs[bi]; --bi; }
                gs[bi + 1] = key;
            }
            for (int t = 0; t < KE; ++t) {
                int g = gs[t];
                float x = bx[g * 3 + 0];
                float y = bx[g * 3 + 1];
                float z = bx[g * 3 + 2];
                float tq  = addrn(addrn(mulrn(x, x), mulrn(y, y)), mulrn(z, z));
                float dot = fmaf(z, qz, fmaf(y, qy, mulrn(x, qx)));
                float d   = subrn(addrn(qsq, tq), mulrn(2.0f, dot));
                if (d < kdm[KE - 1]) {
                    kdm[KE - 1] = d; kim[KE - 1] = g;
#pragma unroll
                    for (int t2 = KE - 1; t2 >= 1; --t2) {
                        if (kdm[t2] < kdm[t2 - 1]) {
                            float td = kdm[t2]; kdm[t2] = kdm[t2 - 1]; kdm[t2 - 1] = td;
                            int   ti = kim[t2]; kim[t2] = kim[t2 - 1]; kim[t2 - 1] = ti;
                        }
                    }
                }
            }
        }
        for (int w2 = 0; w2 < NW; ++w2) {
            int gs[KK];
#pragma unroll
            for (int t = 0; t < KK; ++t) gs[t] = ski64[w2][t][lane];
            for (int a = 1; a < KK; ++a) {
                int key = gs[a]; int bi = a - 1;
                while (bi >= 0 && gs[bi] > key) { gs[bi + 1] = gs[bi]; --bi; }
                gs[bi + 1] = key;
            }
            for (int t = 0; t < KK; ++t) {
                int g = gs[t];
                const float* pg = bx + (size_t)g * 3u;
                float x = pg[0], y = pg[1], z = pg[2];
                double xd = (double)x, yd = (double)y, zd = (double)z;
                double tq64  = xd * xd + yd * yd + zd * zd;
                double dot64 = xd * qxd + yd * qyd + zd * qzd;
                double d64   = qsq64 + tq64 - 2.0 * dot64;
                if (d64 < k64m[KK - 1]) {
                    k64m[KK - 1] = d64; i64m[KK - 1] = g;
#pragma unroll
                    for (int t2 = KK - 1; t2 >= 1; --t2) {
                        if (k64m[t2] < k64m[t2 - 1]) {
                            double td = k64m[t2]; k64m[t2] = k64m[t2 - 1]; k64m[t2 - 1] = td;
                            int    ti = i64m[t2]; i64m[t2] = i64m[t2 - 1]; i64m[t2 - 1] = ti;
                        }
                    }
                }
            }
        }

        bool agree = true;
#pragma unroll
        for (int t = 0; t < KK; ++t) agree = agree && (kim[t] == i64m[t]);

        bool hastie = false;
#pragma unroll
        for (int t = 1; t < KE; ++t) hastie = hastie || (kdm[t] == kdm[t - 1]);

        const bool use_f32 = agree || hastie;
        int kf[KK];
#pragma unroll
        for (int t = 0; t < KK; ++t) kf[t] = use_f32 ? kim[t] : i64m[t];

        float pl[PP];
#pragma unroll
        for (int p = 0; p < PP; ++p) pl[p] = -3.0e38f;

        for (int k = 1; k < KK; ++k) {
            int g = kf[k];
            float rx = bx[g * 3 + 0] - qx;
            float ry = bx[g * 3 + 1] - qy;
            float rz = bx[g * 3 + 2] - qz;
            float nrm  = sqrtf(rx * rx + ry * ry + rz * rz) + 1e-8f;
            float invn = 1.0f / nrm;
            for (int p = 0; p < PP; ++p) {
                float t = rx * wpx[p] + ry * wpy[p] + rz * wpz[p];
                float a = t * invn;
                float v = nrm * a * fabsf(a);
                pl[p] = fmaxf(pl[p], v);
            }
        }

        for (int q = 0; q < QQ; ++q) {
            float acc = 0.0f;
            for (int p = 0; p < PP; ++p) acc = fmaf(pl[p], w_shapes[q * PP + p], acc);
            float y2 = (acc - bmn[q]) * bsc[q] + bbt[q];
            y2 = fmaxf(y2, 0.0f);
            unsigned o = ((unsigned)b * QQ + (unsigned)q) * SS + (unsigned)s;
            out[o] = y2;
        }

        for (int t = 0; t < KK; ++t) {
            unsigned o = OFF_IDX + ((unsigned)b * SS + (unsigned)s) * (unsigned)KK + (unsigned)t;
            out[o] = (float)kf[t];
        }
    }
}

extern "C" void kernel_launch(void* const* d_in, const int* in_sizes, int n_in,
                              void* d_out, int out_size, void* d_ws, size_t ws_size,
                              hipStream_t stream)
{
    const float* xyz      = (const float*)d_in[0];
    const float* w_planes = (const float*)d_in[1];
    const float* w_shapes = (const float*)d_in[2];
    const float* bn_gamma = (const float*)d_in[3];
    const float* bn_beta  = (const float*)d_in[4];
    const float* bn_mean  = (const float*)d_in[5];
    const float* bn_var   = (const float*)d_in[6];

    float* out = (float*)d_out;
    float* ws  = (float*)d_ws;

    const unsigned ws_floats = (unsigned)(ws_size / 4);
    const int use_ws = (ws_size >= (size_t)BB * SS * 3 * 4) ? 1 : 0;

    hipLaunchKernelGGL(fps_kernel, dim3(BB), dim3(FTH), 0, stream,
                       xyz, out, ws, ws_floats);

    hipLaunchKernelGGL(knn_shape_kernel, dim3(BB * NBLK), dim3(KTH), 0, stream,
                       xyz, ws, use_ws, ws_floats,
                       w_planes, w_shapes,
                       bn_gamma, bn_beta, bn_mean, bn_var,
                       out);
}